// Round 1
// 157.579 us; speedup vs baseline: 1.0347x; 1.0347x over previous
//
#include <hip/hip_runtime.h>
#include <hip/hip_fp16.h>
#include <math.h>

// GraphConvolution (GCNII variant=True, residual=True), N=100k, E=1M, D=64.
//   agg[dst] += h[src] * edge_w
//   out = theta*([agg,i]@W) + (1-theta)*((1-alpha)*agg + alpha*i) + i
//
// R9: 4 dispatches, f16 pipeline.
//   convert:  h (f32) -> h16 (f16), W -> frag-packed f16. Pure streaming at
//             full-fill grid (was inside bin_fill at 48% block fill).
//   bin_fill: bin edges by dst>>7 into 128-node buckets (R7-verified logic,
//             conversion removed).
//   spmm:     one block per 64-node HALF-bin (grid 782->1564: fills the
//             1024-block residency; wave serial chain 16->8 nodes). Gather
//             MAC uses v_pk_fma_f16 (__hfma2): 2 packed FMAs replace
//             4 cvt + 4 f32 FMA per lane-edge; agg stays f16 end-to-end
//             (f16 = 10 mantissa bits > bf16's 8 -> absmax should drop).
//             Epilogue: per 16-row MFMA tile, wave pair splits col-tiles.

#define DFEAT 64
#define BINSZ 128        // bucket granularity (dst>>7)
#define NBINS 1024       // physical; logical = ceil(N/128) = 782
#define CAP   2048       // slots per 128-node bucket (mean 1280, sigma ~36)
#define SUBSZ 64         // nodes per spmm block
#define SCAP  1024       // sorted slots per 64-node half (mean 640, sigma ~25)
#define CHUNK 4096       // edges per bin_fill block
#define TPB   512

#define ASTR  72         // agg16 row stride in ushorts (144 B = 9*16, aligned)

typedef unsigned long long u64;
typedef __attribute__((ext_vector_type(8))) _Float16 f16x8;
typedef __attribute__((ext_vector_type(4))) float f32x4;

__device__ inline unsigned h2u(__half2 h) {
    union { __half2 h; unsigned u; } c; c.h = h; return c.u;
}
__device__ inline __half2 u2h(unsigned u) {
    union { unsigned u; __half2 h; } c; c.u = u; return c.h;
}

// ---- phase 0: h (f32)->f16 + W frag-pack (f16), full-fill streaming grid ----
__global__ __launch_bounds__(256) void convert_kernel(
    const float* __restrict__ h, const float* __restrict__ weight,
    ushort* __restrict__ h16, ushort* __restrict__ w16, int total4) {
    int gid = blockIdx.x * 256 + threadIdx.x;
    int nth = gridDim.x * 256;
    for (int i = gid; i < total4; i += nth) {
        float4 v = ((const float4*)h)[i];
        uint2 o;
        o.x = h2u(__floats2half2_rn(v.x, v.y));
        o.y = h2u(__floats2half2_rn(v.z, v.w));
        ((uint2*)h16)[i] = o;
    }
    // W -> frag-packed f16: w16[((c*4+s)*64+l)*8+j]
    //   = f16(W[s*32 + (l>>4)*8 + j][c*16 + (l&15)])   (layout R8-verified)
    if (gid < 8192) {
        int j = gid & 7, l = (gid >> 3) & 63, cs = gid >> 9;
        int c = cs >> 2, s = cs & 3, q = l >> 4, m = l & 15;
        w16[gid] = __half_as_ushort(
            __float2half_rn(weight[(s * 32 + q * 8 + j) * DFEAT + c * 16 + m]));
    }
}

// ---- phase 1: bin edges by dst>>7 into global buckets ----
// Entry: low32 = src | (dstLocal<<24) (dl < 128), high32 = bits(w) (f32).
__global__ __launch_bounds__(512) void bin_fill_kernel(
    const int* __restrict__ e_src, const int* __restrict__ e_dst,
    const float* __restrict__ e_w, int* __restrict__ gcur,
    u64* __restrict__ bucket, int E) {
    __shared__ u64 staging[CHUNK];            // 32 KB
    __shared__ unsigned short binOf[CHUNK];   // 8 KB
    __shared__ int hist[NBINS], offs[NBINS], gbase[NBINS], cur[NBINS]; // 16 KB
    __shared__ int part[TPB];                 // 2 KB

    int tid = threadIdx.x;
    int e0 = blockIdx.x * CHUNK;
    int cc = min(CHUNK, E - e0);

    hist[tid] = 0; hist[tid + 512] = 0;
    __syncthreads();

    int d[8], s[8];
    float w[8];
#pragma unroll
    for (int j = 0; j < 8; ++j) {
        int e = e0 + j * TPB + tid;
        if (e < E) { d[j] = e_dst[e]; s[j] = e_src[e]; w[j] = e_w[e]; }
        else d[j] = -1;
    }
#pragma unroll
    for (int j = 0; j < 8; ++j)
        if (d[j] >= 0) atomicAdd(&hist[d[j] >> 7], 1);
    __syncthreads();

    // exclusive scan of hist[1024]: thread t owns pair (2t, 2t+1)
    int a = hist[2 * tid], b = hist[2 * tid + 1];
    part[tid] = a + b;
    __syncthreads();
    for (int ofs = 1; ofs < TPB; ofs <<= 1) {
        int t = (tid >= ofs) ? part[tid - ofs] : 0;
        __syncthreads();
        part[tid] += t;
        __syncthreads();
    }
    int excl = part[tid] - (a + b);
    offs[2 * tid] = excl;         cur[2 * tid] = excl;
    offs[2 * tid + 1] = excl + a; cur[2 * tid + 1] = excl + a;
    __syncthreads();

    // scatter into bin-sorted LDS staging
#pragma unroll
    for (int j = 0; j < 8; ++j) {
        if (d[j] >= 0) {
            int bb = d[j] >> 7;
            int p = atomicAdd(&cur[bb], 1);
            unsigned lo = (unsigned)s[j] | ((unsigned)(d[j] & 127) << 24);
            staging[p] = ((u64)(unsigned)__float_as_int(w[j]) << 32) | lo;
            binOf[p] = (unsigned short)bb;
        }
    }
    __syncthreads();

    // reserve global space: one atomic per non-empty bin
    for (int t = tid; t < NBINS; t += TPB) {
        int c = hist[t];
        gbase[t] = (c > 0) ? atomicAdd(&gcur[t], c) : 0;
    }
    __syncthreads();

    // flush: bin-contiguous runs -> contiguous global slots
#pragma unroll
    for (int j = 0; j < 8; ++j) {
        int p = j * TPB + tid;
        if (p < cc) {
            int bb = binOf[p];
            bucket[(size_t)bb * CAP + gbase[bb] + (p - offs[bb])] = staging[p];
        }
    }
}

// ---- phase 2: per-64-node-half sort + packed-f16 gather + MFMA epilogue ----
// 512 threads (8 waves), ~18 KB LDS -> 4 blocks/CU (wave-capped), grid 1564.
// Wave wv gathers local nodes [wv*8, wv*8+8). Epilogue: tile t = wv>>1
// (rows 16t..16t+16), wave pair splits the 4 col-tiles 2+2.
__global__ __launch_bounds__(512) void spmm_kernel(
    const ushort* __restrict__ h16, const u64* __restrict__ bucket,
    const int* __restrict__ gcur, const ushort* __restrict__ w16,
    const float* __restrict__ ifeat,
    const float* __restrict__ lamda_p, const float* __restrict__ alpha_p,
    const int* __restrict__ layer_p,
    float* __restrict__ out, int N) {
    __shared__ u64 sorted[SCAP];                          // 8 KB
    __shared__ __align__(16) ushort agg16[SUBSZ * ASTR];  // 9 KB (f16 agg)
    __shared__ int hist[SUBSZ], start[SUBSZ], cur[SUBSZ]; // 768 B

    int tid = threadIdx.x;
    int bin = blockIdx.x >> 1;
    int half = blockIdx.x & 1;
    int lo = half << 6;                 // local-id range [lo, lo+64)
    int base = (bin << 7) + lo;
    int cnt = gcur[bin];
    const u64* bk = bucket + (size_t)bin * CAP;

    if (tid < SUBSZ) hist[tid] = 0;
    __syncthreads();

    // histogram of this half's local node ids
    for (int p = tid; p < cnt; p += TPB) {
        int dl = (int)((((unsigned)bk[p]) >> 24) & 127);
        if ((dl & 64) == lo) atomicAdd(&hist[dl & 63], 1);
    }
    __syncthreads();

    // wave-0 shfl exclusive scan over 64 counters (no barrier loop)
    if (tid < 64) {
        int v = hist[tid];
        int s = v;
#pragma unroll
        for (int ofs = 1; ofs < 64; ofs <<= 1) {
            int t = __shfl_up(s, ofs);
            if (tid >= ofs) s += t;
        }
        start[tid] = s - v;
        cur[tid] = s - v;
    }
    __syncthreads();

    // permute this half's edges into node-sorted LDS
    for (int p = tid; p < cnt; p += TPB) {
        u64 e = bk[p];
        int dl = (int)((((unsigned)e) >> 24) & 127);
        if ((dl & 64) == lo) {
            int pos = atomicAdd(&cur[dl & 63], 1);
            sorted[pos] = e;
        }
    }
    __syncthreads();

    int lane = tid & 63, wv = tid >> 6;
    int g = lane >> 4, m = lane & 15;
    int nn = min(SUBSZ, N - base);

    // gather: quad g owns edge t0+s*4+g, lane covers features m*4..m*4+3
    // packed as two __half2. Wave wv fills agg16 rows [wv*8, wv*8+8).
    for (int k = 0; k < 8; ++k) {
        int nl = (wv << 3) + k;
        if (nl >= nn) break;
        int d = hist[nl];
        int b0 = start[nl];
        __half2 a01 = u2h(0u), a23 = u2h(0u);
        for (int t0 = 0; t0 < d; t0 += 16) {
#pragma unroll
            for (int s = 0; s < 4; ++s) {
                int idx = t0 + (s << 2) + g;
                u64 e = sorted[b0 + min(idx, d - 1)];
                float wf = (idx < d) ? __int_as_float((int)(e >> 32)) : 0.f;
                __half2 w2 = __float2half2_rn(wf);
                unsigned src = ((unsigned)e) & 0xFFFFFFu;
                uint2 hv = *(const uint2*)(h16 + ((size_t)src << 6) + (m << 2));
                a01 = __hfma2(w2, u2h(hv.x), a01);
                a23 = __hfma2(w2, u2h(hv.y), a23);
            }
        }
        a01 = __hadd2(a01, u2h((unsigned)__shfl_xor((int)h2u(a01), 16)));
        a23 = __hadd2(a23, u2h((unsigned)__shfl_xor((int)h2u(a23), 16)));
        a01 = __hadd2(a01, u2h((unsigned)__shfl_xor((int)h2u(a01), 32)));
        a23 = __hadd2(a23, u2h((unsigned)__shfl_xor((int)h2u(a23), 32)));
        if (g == 0) {
            uint2 o; o.x = h2u(a01); o.y = h2u(a23);
            *(uint2*)(agg16 + nl * ASTR + (m << 2)) = o;
        }
    }
    __syncthreads();   // epilogue tile rows span two waves' gather output

    // fused epilogue: tile t = wv>>1 (16 rows), col-tiles {2ch, 2ch+1}
    float alf = alpha_p[0];
    float theta = fminf(1.0f, logf(lamda_p[0] / (float)layer_p[0] + 1.0f));
    int q = g;
    int t = wv >> 1, ch = wv & 1;

    f16x8 faA[2], faI[2];
#pragma unroll
    for (int s = 0; s < 2; ++s)
        faA[s] = *(const f16x8*)(agg16 + (t * 16 + m) * ASTR + s * 32 + q * 8);
    {
        const float* ip = ifeat + (size_t)min(base + t * 16 + m, N - 1) * DFEAT;
#pragma unroll
        for (int s = 0; s < 2; ++s) {
            float4 v0 = *(const float4*)(ip + s * 32 + q * 8);
            float4 v1 = *(const float4*)(ip + s * 32 + q * 8 + 4);
            f16x8 tt;
            tt[0] = (_Float16)v0.x; tt[1] = (_Float16)v0.y;
            tt[2] = (_Float16)v0.z; tt[3] = (_Float16)v0.w;
            tt[4] = (_Float16)v1.x; tt[5] = (_Float16)v1.y;
            tt[6] = (_Float16)v1.z; tt[7] = (_Float16)v1.w;
            faI[s] = tt;
        }
    }

    f32x4 acc[2] = {{0.f, 0.f, 0.f, 0.f}, {0.f, 0.f, 0.f, 0.f}};
#pragma unroll
    for (int ci = 0; ci < 2; ++ci) {
        int c = ch * 2 + ci;
#pragma unroll
        for (int s = 0; s < 2; ++s) {
            f16x8 bA = *(const f16x8*)(w16 + ((c * 4 + s) * 64 + lane) * 8);
            acc[ci] = __builtin_amdgcn_mfma_f32_16x16x32_f16(faA[s], bA, acc[ci], 0, 0, 0);
            f16x8 bI = *(const f16x8*)(w16 + ((c * 4 + s + 2) * 64 + lane) * 8);
            acc[ci] = __builtin_amdgcn_mfma_f32_16x16x32_f16(faI[s], bI, acc[ci], 0, 0, 0);
        }
    }

    // mix + residual + store (C/D: row = t*16 + q*4 + r, col = c*16 + m)
#pragma unroll
    for (int ci = 0; ci < 2; ++ci) {
        int c = ch * 2 + ci;
        int col = c * 16 + m;
#pragma unroll
        for (int r = 0; r < 4; ++r) {
            int rowL = t * 16 + q * 4 + r;
            int row = base + rowL;
            if (row < N) {
                float av = __half2float(
                    *(const __half*)(agg16 + rowL * ASTR + col));
                float iv = ifeat[(size_t)row * DFEAT + col];
                out[(size_t)row * DFEAT + col] =
                    theta * acc[ci][r] +
                    (1.f - theta) * ((1.f - alf) * av + alf * iv) + iv;
            }
        }
    }
}

extern "C" void kernel_launch(void* const* d_in, const int* in_sizes, int n_in,
                              void* d_out, int out_size, void* d_ws, size_t ws_size,
                              hipStream_t stream) {
    const float* h       = (const float*)d_in[0];
    const float* ifeat   = (const float*)d_in[1];
    const float* weight  = (const float*)d_in[2];
    const float* edge_w  = (const float*)d_in[3];
    const float* lamda_p = (const float*)d_in[4];
    const float* alpha_p = (const float*)d_in[5];
    const int*   e_src   = (const int*)d_in[6];
    const int*   e_dst   = (const int*)d_in[7];
    const int*   layer_p = (const int*)d_in[8];
    float* out = (float*)d_out;

    int N = in_sizes[0] / DFEAT;       // 100000
    int E = in_sizes[3];               // 1000000
    int nbins = (N + BINSZ - 1) >> 7;  // 782

    // ws: gcur[1024] (4KB) | bucket 16.78MB | h16 12.8MB | w16 16KB
    int* gcur = (int*)d_ws;
    u64* bucket = (u64*)((char*)d_ws + 4096);
    ushort* h16 = (ushort*)((char*)bucket + (size_t)NBINS * CAP * sizeof(u64));
    ushort* w16 = h16 + (size_t)N * DFEAT;

    hipMemsetAsync(gcur, 0, NBINS * sizeof(int), stream);

    int total4 = N * DFEAT / 4;
    convert_kernel<<<2048, 256, 0, stream>>>(h, weight, h16, w16, total4);

    bin_fill_kernel<<<(E + CHUNK - 1) / CHUNK, TPB, 0, stream>>>(
        e_src, e_dst, edge_w, gcur, bucket, E);

    spmm_kernel<<<nbins * 2, TPB, 0, stream>>>(
        h16, bucket, gcur, w16, ifeat, lamda_p, alpha_p, layer_p, out, N);
}